// Round 14
// baseline (349.314 us; speedup 1.0000x reference)
//
#include <hip/hip_runtime.h>
#include <hip/hip_bf16.h>

constexpr int BB = 32;     // batches
constexpr int P  = 1024;   // patches per batch
constexpr int O  = 128;    // objects per batch
constexpr int D  = 512;    // feature dim
constexpr float EPS = 1e-8f;
constexpr float SCL = 14.426950408889634f; // (1/0.1) * log2(e)

typedef __attribute__((ext_vector_type(8))) short short8;
typedef __attribute__((ext_vector_type(16))) float f32x16;

__device__ __forceinline__ unsigned short f2bf(float f) {
  __hip_bfloat16 h = __float2bfloat16(f);
  unsigned short u;
  __builtin_memcpy(&u, &h, sizeof(u));
  return u;
}

__device__ __forceinline__ void gld_lds16(const void* g, void* l) {
  __builtin_amdgcn_global_load_lds(
      (const __attribute__((address_space(1))) void*)g,
      (__attribute__((address_space(3))) void*)l, 16, 0, 0);
}

// ---- prep2: feature normalize->bf16 AND mask compression (one launch) ----
// blocks [0,FB): features; [FB,FB+JB): e1j bitmask; [FB+JB,FB+2JB): e1i/e2j
constexpr int FB = (BB * P + BB * O) / 4;   // 9216
constexpr int JB = (BB * P) / 4;            // 8192
__global__ __launch_bounds__(256) void prep2_kernel(
    const float* __restrict__ pf, const float* __restrict__ of,
    const float* __restrict__ e1i, const float* __restrict__ e1j,
    const float* __restrict__ e2j,
    __hip_bfloat16* __restrict__ pn, __hip_bfloat16* __restrict__ on,
    unsigned long long* __restrict__ bm1j, unsigned long long* __restrict__ bm2j,
    int* __restrict__ posr) {
  const int lane = threadIdx.x & 63;
  const int wid4 = threadIdx.x >> 6;
  const int bid  = blockIdx.x;

  if (bid < FB) {
    int row = bid * 4 + wid4;
    const float* src;
    __hip_bfloat16* dst;
    if (row < BB * P) {
      src = pf + (size_t)row * D;
      dst = pn + (size_t)row * D;
    } else {
      int r = row - BB * P;
      if (r >= BB * O) return;
      src = of + (size_t)r * D;
      dst = on + (size_t)r * D;
    }
    float4 v0 = *(const float4*)(src + lane * 8);
    float4 v1 = *(const float4*)(src + lane * 8 + 4);
    float ss = v0.x * v0.x + v0.y * v0.y + v0.z * v0.z + v0.w * v0.w +
               v1.x * v1.x + v1.y * v1.y + v1.z * v1.z + v1.w * v1.w;
    #pragma unroll
    for (int s = 1; s < 64; s <<= 1) ss += __shfl_xor(ss, s);
    float sc = 1.0f / fmaxf(sqrtf(ss), 1e-12f);
    short8 w;
    w[0] = (short)f2bf(v0.x * sc); w[1] = (short)f2bf(v0.y * sc);
    w[2] = (short)f2bf(v0.z * sc); w[3] = (short)f2bf(v0.w * sc);
    w[4] = (short)f2bf(v1.x * sc); w[5] = (short)f2bf(v1.y * sc);
    w[6] = (short)f2bf(v1.z * sc); w[7] = (short)f2bf(v1.w * sc);
    *reinterpret_cast<short8*>(dst + lane * 8) = w;
  } else if (bid < FB + JB) {
    // e1j: one row (1024 floats) per wave, float4 loads; lane i covers cols
    // [16i,16i+16); word j bit b <-> col 64j+b (standard layout)
    const int row = (bid - FB) * 4 + wid4;
    const float* src = e1j + (size_t)row * P;
    unsigned bits = 0;
    #pragma unroll
    for (int c = 0; c < 4; ++c) {
      float4 v = *(const float4*)(src + lane * 16 + c * 4);
      bits |= ((v.x > 0.5f) ? 1u : 0u) << (c * 4);
      bits |= ((v.y > 0.5f) ? 1u : 0u) << (c * 4 + 1);
      bits |= ((v.z > 0.5f) ? 1u : 0u) << (c * 4 + 2);
      bits |= ((v.w > 0.5f) ? 1u : 0u) << (c * 4 + 3);
    }
    unsigned long long wbits = (unsigned long long)bits << ((lane & 3) * 16);
    wbits |= __shfl_xor(wbits, 1);
    wbits |= __shfl_xor(wbits, 2);
    if ((lane & 3) == 0) bm1j[(size_t)row * 16 + (lane >> 2)] = wbits;
  } else {
    // e1i one-hot position + e2j bitmask: one row per wave
    const int row = (bid - FB - JB) * 4 + wid4;
    unsigned long long b0 = __ballot(e1i[(size_t)row * O + lane] > 0.5f);
    unsigned long long b1 = __ballot(e1i[(size_t)row * O + 64 + lane] > 0.5f);
    unsigned long long d0 = __ballot(e2j[(size_t)row * O + lane] > 0.5f);
    unsigned long long d1 = __ballot(e2j[(size_t)row * O + 64 + lane] > 0.5f);
    if (lane == 0) {
      posr[row] = b0 ? (__ffsll(b0) - 1) : (b1 ? 63 + __ffsll(b1) : -1);
      bm2j[(size_t)row * 2]     = d0;
      bm2j[(size_t)row * 2 + 1] = d1;
    }
  }
}

// ---- main v14: v10 verbatim, launch_bounds(256,5) -- residency was the ----
// binding constraint (LDS 32KB -> 5 blocks/CU fit; VGPR 56 << cap 102).
// 128x128 tile, BK=64, 4 waves (each 64x64 = acc[2][2]).
// grid = 32 batches x 8 rowtiles x 9 coltiles (ct 0 = objects).
__global__ __launch_bounds__(256, 5) void icl_main14(
    const __hip_bfloat16* __restrict__ pn, const __hip_bfloat16* __restrict__ on,
    const unsigned long long* __restrict__ bm1j,
    const unsigned long long* __restrict__ bm2j,
    const int* __restrict__ posr,
    float* __restrict__ d_row, float* __restrict__ s1_row,
    float* __restrict__ s2_row, unsigned long long* __restrict__ pk_row) {

  // XOR-swizzled (pre-swizzled global source): 16B chunk c of row r at c^(r&7)
  __shared__ __hip_bfloat16 As[128 * 64];   // 16 KB
  __shared__ __hip_bfloat16 Bs[128 * 64];   // 16 KB

  const int tid  = threadIdx.x;
  const int l    = tid & 63;
  const int wid  = tid >> 6;
  const int wr   = wid >> 1;    // row-group: rows wr*64..+63
  const int wc   = wid & 1;     // col-group: cols wc*64..+63
  const int half = l >> 5;
  const int l31  = l & 31;

  const int bid   = blockIdx.x;
  const int batch = bid & 31;          // same-batch blocks -> same XCD (b%8)
  const int unit  = bid >> 5;          // 0..71
  const int rt    = unit & 7;          // 8 row tiles
  const int ct    = unit >> 3;         // 9 col tiles (0 = objects)
  const int row0  = rt * 128;

  const __hip_bfloat16* pnb = pn + (size_t)batch * P * D;
  const __hip_bfloat16* onb = on + (size_t)batch * O * D;
  const __hip_bfloat16* asrc = pnb + (size_t)row0 * D;
  const __hip_bfloat16* bsrc = (ct == 0) ? onb : pnb + (size_t)(ct - 1) * 128 * D;

  // stage one 128x64 bf16 tile (1024 16B chunks) via global_load_lds:
  // dest linear (chunk q at byte q*16), source pre-swizzled: gc = c ^ (r&7)
  auto stage = [&](const __hip_bfloat16* __restrict__ src,
                   __hip_bfloat16* __restrict__ lds, int k0) {
    #pragma unroll
    for (int i = 0; i < 4; ++i) {
      int q = i * 256 + tid;
      int rr = q >> 3, c = q & 7;
      int gc = c ^ (rr & 7);
      gld_lds16(src + (size_t)rr * D + k0 + (gc << 3),
                (char*)lds + (size_t)(i * 256 + wid * 64) * 16);
    }
  };

  f32x16 acc[2][2];
  #pragma unroll
  for (int m = 0; m < 2; ++m)
    #pragma unroll
    for (int n = 0; n < 2; ++n)
      #pragma unroll
      for (int k = 0; k < 16; ++k) acc[m][n][k] = 0.f;

  for (int ks = 0; ks < 8; ++ks) {
    __syncthreads();                 // previous step's LDS reads done
    stage(asrc, As, ks * 64);
    stage(bsrc, Bs, ks * 64);
    __syncthreads();                 // staged tiles visible (vmcnt drained)
    #pragma unroll
    for (int kc = 0; kc < 4; ++kc) {
      const int ch = (kc << 1) | half;
      short8 af[2], bfr[2];
      #pragma unroll
      for (int m = 0; m < 2; ++m) {
        int row = wr * 64 + m * 32 + l31;
        af[m] = *reinterpret_cast<const short8*>(
            As + row * 64 + ((ch ^ (row & 7)) << 3));
      }
      #pragma unroll
      for (int n = 0; n < 2; ++n) {
        int col = wc * 64 + n * 32 + l31;
        bfr[n] = *reinterpret_cast<const short8*>(
            Bs + col * 64 + ((ch ^ (col & 7)) << 3));
      }
      #pragma unroll
      for (int m = 0; m < 2; ++m)
        #pragma unroll
        for (int n = 0; n < 2; ++n)
          acc[m][n] = __builtin_amdgcn_mfma_f32_32x32x16_bf16(
              af[m], bfr[n], acc[m][n], 0, 0, 0);
    }
  }

  // ---- epilogue: bitmask row-sums + argmax, atomic combine across blocks --
  if (ct == 0) {
    #pragma unroll
    for (int m = 0; m < 2; ++m) {
      #pragma unroll
      for (int r = 0; r < 16; ++r) {
        const int lrow = wr * 64 + m * 32 + (r & 3) + ((r >> 2) << 3) + (half << 2);
        const size_t grow = (size_t)batch * P + row0 + lrow;
        const int pos = posr[grow];
        const unsigned long long W2 = bm2j[grow * 2 + wc];
        const int c0 = wc * 64 + l31, c1 = c0 + 32;
        float s0 = acc[m][0][r], s1v = acc[m][1][r];
        float e0 = exp2f(s0 * SCL), e1v = exp2f(s1v * SCL);
        float dv  = (c0 == pos ? e0 : 0.f) + (c1 == pos ? e1v : 0.f);
        float s2v = (((W2 >> l31) & 1) ? e0 : 0.f) +
                    (((W2 >> (32 + l31)) & 1) ? e1v : 0.f);
        float mvv; int miv;
        if (s1v > s0) { mvv = s1v; miv = c1; } else { mvv = s0; miv = c0; }
        #pragma unroll
        for (int s = 1; s < 32; s <<= 1) {
          dv  += __shfl_xor(dv, s);
          s2v += __shfl_xor(s2v, s);
          float ov = __shfl_xor(mvv, s);
          int   oi = __shfl_xor(miv, s);
          if (ov > mvv || (ov == mvv && oi < miv)) { mvv = ov; miv = oi; }
        }
        if (l31 == 0) {
          if (dv != 0.f) atomicAdd(&d_row[grow], dv);
          atomicAdd(&s2_row[grow], s2v);
          unsigned long long pkv =
              ((unsigned long long)__float_as_uint(mvv + 2.0f) << 32) |
              (unsigned)(0xFFFFFFFFu - (unsigned)miv);
          atomicMax(&pk_row[grow], pkv);
        }
      }
    }
  } else {
    const int widx = (ct - 1) * 2 + wc;     // u64 word covering this 64-col grp
    #pragma unroll
    for (int m = 0; m < 2; ++m) {
      #pragma unroll
      for (int r = 0; r < 16; ++r) {
        const int lrow = wr * 64 + m * 32 + (r & 3) + ((r >> 2) << 3) + (half << 2);
        const size_t grow = (size_t)batch * P + row0 + lrow;
        const unsigned long long W = bm1j[grow * 16 + widx];
        float v = (((W >> l31) & 1) ? exp2f(acc[m][0][r] * SCL) : 0.f) +
                  (((W >> (32 + l31)) & 1) ? exp2f(acc[m][1][r] * SCL) : 0.f);
        #pragma unroll
        for (int s = 1; s < 32; s <<= 1) v += __shfl_xor(v, s);
        if (l31 == 0 && v != 0.f) atomicAdd(&s1_row[grow], v);
      }
    }
  }
}

// ---------------- per-row loss + scalar reduction --------------------------
__global__ __launch_bounds__(256) void icl_reduce2(
    const float* __restrict__ d_row, const float* __restrict__ s1_row,
    const float* __restrict__ s2_row, const unsigned long long* __restrict__ pk_row,
    const int* __restrict__ posr, float* __restrict__ accum) {
  __shared__ float red[12];
  const int tid = threadIdx.x;
  const int row = blockIdx.x * 256 + tid;
  float d = d_row[row], a = s1_row[row], c = s2_row[row];
  int pos = posr[row];
  int miv = (int)(0xFFFFFFFFu - (unsigned)(pk_row[row] & 0xFFFFFFFFull));
  float valid = (pos >= 0) ? 1.f : 0.f;
  float ratio = d / (d + a + c + EPS);
  float lsum = -logf(ratio + EPS) * valid;
  float lbl  = (pos >= 0 && miv == pos) ? 1.f : 0.f;
  float vct  = valid;
  #pragma unroll
  for (int s = 1; s < 64; s <<= 1) {
    lsum += __shfl_xor(lsum, s);
    lbl  += __shfl_xor(lbl, s);
    vct  += __shfl_xor(vct, s);
  }
  const int wid = tid >> 6;
  if ((tid & 63) == 0) {
    red[wid * 3 + 0] = lsum;
    red[wid * 3 + 1] = lbl;
    red[wid * 3 + 2] = vct;
  }
  __syncthreads();
  if (tid == 0) {
    atomicAdd(&accum[0], red[0] + red[3] + red[6] + red[9]);
    atomicAdd(&accum[1], red[1] + red[4] + red[7] + red[10]);
    atomicAdd(&accum[2], red[2] + red[5] + red[8] + red[11]);
  }
}

__global__ void finalize_kernel(const float* __restrict__ accum,
                                float* __restrict__ out) {
  if (threadIdx.x == 0 && blockIdx.x == 0) {
    float nv = accum[2];
    out[0] = accum[0] / nv;
    out[1] = accum[1] / nv;
  }
}

// ---------------- fallback path (round-1, known correct) -------------------
__global__ __launch_bounds__(256) void norm_kernel(
    const float* __restrict__ pf, const float* __restrict__ of,
    float* __restrict__ invp, float* __restrict__ invo) {
  int lane = threadIdx.x & 63;
  int row = blockIdx.x * 4 + (threadIdx.x >> 6);
  const float* src;
  float* dst;
  if (row < BB * P) {
    src = pf + (size_t)row * D;
    dst = invp + row;
  } else {
    int r = row - BB * P;
    if (r >= BB * O) return;
    src = of + (size_t)r * D;
    dst = invo + r;
  }
  float ss = 0.f;
  #pragma unroll
  for (int i = 0; i < 2; ++i) {
    float4 v = *(const float4*)(src + (lane + 64 * i) * 4);
    ss += v.x * v.x + v.y * v.y + v.z * v.z + v.w * v.w;
  }
  #pragma unroll
  for (int s = 1; s < 64; s <<= 1) ss += __shfl_xor(ss, s);
  if (lane == 0) *dst = 1.0f / fmaxf(sqrtf(ss), 1e-12f);
}

__global__ __launch_bounds__(256) void icl_main_v1(
    const float* __restrict__ pf, const float* __restrict__ of,
    const float* __restrict__ e1i, const float* __restrict__ e1j,
    const float* __restrict__ e2j, const float* __restrict__ invp,
    const float* __restrict__ invo, float* __restrict__ accum) {
  constexpr int PT = 128, BK = 64;
  __shared__ __hip_bfloat16 As[PT * BK];
  __shared__ __hip_bfloat16 Bs[PT * BK];
  __shared__ float d_l[2][PT], s2_l[2][PT], ei_l[2][PT], s1_l[2][PT], mv_l[2][PT];
  __shared__ int   mi_l[2][PT];
  __shared__ float red[12];

  const int tid  = threadIdx.x;
  const int lane = tid & 63;
  const int wid  = tid >> 6;
  const int wr   = wid >> 1;
  const int wc   = wid & 1;
  const int half = lane >> 5;
  const int l31  = lane & 31;
  const int b    = blockIdx.x & 31;
  const int pt   = blockIdx.x >> 5;
  const int row0 = pt * PT;

  const float* pfb = pf + (size_t)b * P * D;
  const float* ofb = of + (size_t)b * O * D;
  const float* ivp = invp + b * P + row0;
  const float* ivq = invp + b * P;
  const float* ivo = invo + b * O;

  float s1p[2][16];
  #pragma unroll
  for (int m = 0; m < 2; ++m)
    #pragma unroll
    for (int r = 0; r < 16; ++r) s1p[m][r] = 0.f;

  auto stage = [&](const float* __restrict__ src, const float* __restrict__ inv,
                   __hip_bfloat16* __restrict__ lds, int k0) {
    #pragma unroll
    for (int i = 0; i < 8; ++i) {
      int c = i * 256 + tid;
      int rr = c >> 4, kc = c & 15;
      float4 v = *(const float4*)(src + (size_t)rr * D + k0 + (kc << 2));
      float s = inv[rr];
      int off = rr * BK + ((((kc >> 1) ^ (rr & 7)) << 3) | ((kc & 1) << 2));
      ushort4 w;
      w.x = f2bf(v.x * s);
      w.y = f2bf(v.y * s);
      w.z = f2bf(v.z * s);
      w.w = f2bf(v.w * s);
      *reinterpret_cast<ushort4*>(lds + off) = w;
    }
  };

  for (int ct = 0; ct < 9; ++ct) {
    const float* bsrc = (ct == 0) ? ofb : pfb + (size_t)(ct - 1) * 128 * D;
    const float* binv = (ct == 0) ? ivo : ivq + (ct - 1) * 128;

    f32x16 acc[2][2];
    #pragma unroll
    for (int m = 0; m < 2; ++m)
      #pragma unroll
      for (int n = 0; n < 2; ++n)
        #pragma unroll
        for (int k = 0; k < 16; ++k) acc[m][n][k] = 0.f;

    for (int ks = 0; ks < D / BK; ++ks) {
      __syncthreads();
      stage(pfb + (size_t)row0 * D, ivp, As, ks * BK);
      stage(bsrc, binv, Bs, ks * BK);
      __syncthreads();
      #pragma unroll
      for (int kc = 0; kc < 4; ++kc) {
        short8 af[2], bfr[2];
        #pragma unroll
        for (int m = 0; m < 2; ++m) {
          int row = wr * 64 + m * 32 + l31;
          af[m] = *reinterpret_cast<const short8*>(
              As + row * BK + ((((kc << 1) | half) ^ (row & 7)) << 3));
        }
        #pragma unroll
        for (int n = 0; n < 2; ++n) {
          int col = wc * 64 + n * 32 + l31;
          bfr[n] = *reinterpret_cast<const short8*>(
              Bs + col * BK + ((((kc << 1) | half) ^ (col & 7)) << 3));
        }
        #pragma unroll
        for (int m = 0; m < 2; ++m)
          #pragma unroll
          for (int n = 0; n < 2; ++n)
            acc[m][n] = __builtin_amdgcn_mfma_f32_32x32x16_bf16(
                af[m], bfr[n], acc[m][n], 0, 0, 0);
      }
    }

    if (ct == 0) {
      #pragma unroll
      for (int m = 0; m < 2; ++m) {
        #pragma unroll
        for (int r = 0; r < 16; ++r) {
          int lrow = wr * 64 + m * 32 + (r & 3) + ((r >> 2) << 3) + (half << 2);
          size_t base = ((size_t)b * P + row0 + lrow) * O;
          float dsum = 0.f, s2s = 0.f, eis = 0.f, mval = -1e30f;
          int midx = 0;
          #pragma unroll
          for (int n = 0; n < 2; ++n) {
            int col = wc * 64 + n * 32 + l31;
            float sim = acc[m][n][r];
            float e = exp2f(sim * SCL);
            float v1 = e1i[base + col];
            float v2 = e2j[base + col];
            dsum += v1 * e;
            s2s  += v2 * e;
            eis  += v1;
            if (sim > mval) { mval = sim; midx = col; }
          }
          #pragma unroll
          for (int s = 1; s < 32; s <<= 1) {
            dsum += __shfl_xor(dsum, s);
            s2s  += __shfl_xor(s2s, s);
            eis  += __shfl_xor(eis, s);
            float ov = __shfl_xor(mval, s);
            int   oi = __shfl_xor(midx, s);
            if (ov > mval || (ov == mval && oi < midx)) { mval = ov; midx = oi; }
          }
          if (l31 == 0) {
            d_l[wc][lrow] = dsum;
            s2_l[wc][lrow] = s2s;
            ei_l[wc][lrow] = eis;
            mv_l[wc][lrow] = mval;
            mi_l[wc][lrow] = midx;
          }
        }
      }
    } else {
      const int qbase = (ct - 1) * 128;
      #pragma unroll
      for (int m = 0; m < 2; ++m) {
        #pragma unroll
        for (int r = 0; r < 16; ++r) {
          int lrow = wr * 64 + m * 32 + (r & 3) + ((r >> 2) << 3) + (half << 2);
          size_t base = ((size_t)b * P + row0 + lrow) * P + qbase;
          float s = 0.f;
          #pragma unroll
          for (int n = 0; n < 2; ++n) {
            int col = wc * 64 + n * 32 + l31;
            s += e1j[base + col] * exp2f(acc[m][n][r] * SCL);
          }
          s1p[m][r] += s;
        }
      }
    }
  }

  #pragma unroll
  for (int m = 0; m < 2; ++m) {
    #pragma unroll
    for (int r = 0; r < 16; ++r) {
      float v = s1p[m][r];
      #pragma unroll
      for (int s = 1; s < 32; s <<= 1) v += __shfl_xor(v, s);
      if (l31 == 0) {
        int lrow = wr * 64 + m * 32 + (r & 3) + ((r >> 2) << 3) + (half << 2);
        s1_l[wc][lrow] = v;
      }
    }
  }
  __syncthreads();

  float lsum = 0.f, lbl = 0.f, vct = 0.f;
  if (tid < PT) {
    float delta = d_l[0][tid] + d_l[1][tid];
    float s2 = s2_l[0][tid] + s2_l[1][tid];
    float eis = ei_l[0][tid] + ei_l[1][tid];
    float s1 = s1_l[0][tid] + s1_l[1][tid];
    float m0 = mv_l[0][tid], m1 = mv_l[1][tid];
    int mi = (m1 > m0) ? mi_l[1][tid] : mi_l[0][tid];
    float valid = (eis > 0.f) ? 1.f : 0.f;
    float ratio = delta / (delta + s1 + s2 + EPS);
    float loss = -logf(ratio + EPS);
    float label = e1i[((size_t)b * P + row0 + tid) * O + mi];
    lsum = loss * valid;
    lbl  = label * valid;
    vct  = valid;
  }
  #pragma unroll
  for (int s = 1; s < 64; s <<= 1) {
    lsum += __shfl_xor(lsum, s);
    lbl  += __shfl_xor(lbl, s);
    vct  += __shfl_xor(vct, s);
  }
  if (lane == 0) {
    red[wid * 3 + 0] = lsum;
    red[wid * 3 + 1] = lbl;
    red[wid * 3 + 2] = vct;
  }
  __syncthreads();
  if (tid == 0) {
    float a = red[0] + red[3] + red[6] + red[9];
    float c = red[1] + red[4] + red[7] + red[10];
    float v = red[2] + red[5] + red[8] + red[11];
    atomicAdd(&accum[0], a);
    atomicAdd(&accum[1], c);
    atomicAdd(&accum[2], v);
  }
}

extern "C" void kernel_launch(void* const* d_in, const int* in_sizes, int n_in,
                              void* d_out, int out_size, void* d_ws, size_t ws_size,
                              hipStream_t stream) {
  const float* pf  = (const float*)d_in[0];
  const float* of  = (const float*)d_in[1];
  const float* e1i = (const float*)d_in[2];
  const float* e1j = (const float*)d_in[3];
  const float* e2j = (const float*)d_in[4];

  char* base = (char*)d_ws;
  constexpr size_t NR = (size_t)BB * P;               // 32768 rows
  float* accum               = (float*)base;                       // 64 B
  float* d_row               = (float*)(base + 64);
  float* s1_row              = (float*)(base + 64 + 4 * NR);
  float* s2_row              = (float*)(base + 64 + 8 * NR);
  unsigned long long* pk_row = (unsigned long long*)(base + 64 + 12 * NR);
  unsigned long long* bm1j   = (unsigned long long*)(base + 64 + 20 * NR); // 128B/row
  unsigned long long* bm2j   = (unsigned long long*)(base + 64 + 148 * NR); // 16B/row
  int* posr                  = (int*)(base + 64 + 164 * NR);
  __hip_bfloat16* pn         = (__hip_bfloat16*)(base + 64 + 168 * NR);
  const size_t pn_bytes = (size_t)BB * P * D * 2;
  const size_t on_bytes = (size_t)BB * O * D * 2;
  __hip_bfloat16* on         = (__hip_bfloat16*)(base + 64 + 168 * NR + pn_bytes);
  const size_t need = 64 + 168 * NR + pn_bytes + on_bytes;

  if (ws_size >= need) {
    hipMemsetAsync(base, 0, 64 + 20 * NR, stream);      // accum,d,s1,s2,pk
    prep2_kernel<<<FB + 2 * JB, 256, 0, stream>>>(pf, of, e1i, e1j, e2j,
                                                  pn, on, bm1j, bm2j, posr);
    icl_main14<<<BB * 72, 256, 0, stream>>>(pn, on, bm1j, bm2j, posr,
                                            d_row, s1_row, s2_row, pk_row);
    icl_reduce2<<<NR / 256, 256, 0, stream>>>(d_row, s1_row, s2_row, pk_row,
                                              posr, accum);
  } else {
    float* ws   = (float*)d_ws;
    float* invp = ws + 16;
    float* invo = ws + 16 + BB * P;
    hipMemsetAsync(accum, 0, 16 * sizeof(float), stream);
    norm_kernel<<<(BB * P + BB * O) / 4, 256, 0, stream>>>(pf, of, invp, invo);
    icl_main_v1<<<BB * (P / 128), 256, 0, stream>>>(pf, of, e1i, e1j, e2j,
                                                    invp, invo, accum);
  }
  finalize_kernel<<<1, 64, 0, stream>>>(accum, (float*)d_out);
}

// Round 15
// 157.648 us; speedup vs baseline: 2.2158x; 2.2158x over previous
//
#include <hip/hip_runtime.h>
#include <hip/hip_bf16.h>

constexpr int BB = 32;     // batches
constexpr int P  = 1024;   // patches per batch
constexpr int O  = 128;    // objects per batch
constexpr int D  = 512;    // feature dim
constexpr float EPS = 1e-8f;
constexpr float SCL = 14.426950408889634f; // (1/0.1) * log2(e)

typedef __attribute__((ext_vector_type(8))) short short8;
typedef __attribute__((ext_vector_type(16))) float f32x16;

__device__ __forceinline__ unsigned short f2bf(float f) {
  __hip_bfloat16 h = __float2bfloat16(f);
  unsigned short u;
  __builtin_memcpy(&u, &h, sizeof(u));
  return u;
}

__device__ __forceinline__ void gld_lds16(const void* g, void* l) {
  __builtin_amdgcn_global_load_lds(
      (const __attribute__((address_space(1))) void*)g,
      (__attribute__((address_space(3))) void*)l, 16, 0, 0);
}

// ---- prep2: feature normalize->bf16 AND mask compression (one launch) ----
// blocks [0,FB): features; [FB,FB+JB): e1j bitmask; [FB+JB,FB+2JB): e1i/e2j
constexpr int FB = (BB * P + BB * O) / 4;   // 9216
constexpr int JB = (BB * P) / 4;            // 8192
__global__ __launch_bounds__(256) void prep2_kernel(
    const float* __restrict__ pf, const float* __restrict__ of,
    const float* __restrict__ e1i, const float* __restrict__ e1j,
    const float* __restrict__ e2j,
    __hip_bfloat16* __restrict__ pn, __hip_bfloat16* __restrict__ on,
    unsigned long long* __restrict__ bm1j, unsigned long long* __restrict__ bm2j,
    int* __restrict__ posr) {
  const int lane = threadIdx.x & 63;
  const int wid4 = threadIdx.x >> 6;
  const int bid  = blockIdx.x;

  if (bid < FB) {
    int row = bid * 4 + wid4;
    const float* src;
    __hip_bfloat16* dst;
    if (row < BB * P) {
      src = pf + (size_t)row * D;
      dst = pn + (size_t)row * D;
    } else {
      int r = row - BB * P;
      if (r >= BB * O) return;
      src = of + (size_t)r * D;
      dst = on + (size_t)r * D;
    }
    float4 v0 = *(const float4*)(src + lane * 8);
    float4 v1 = *(const float4*)(src + lane * 8 + 4);
    float ss = v0.x * v0.x + v0.y * v0.y + v0.z * v0.z + v0.w * v0.w +
               v1.x * v1.x + v1.y * v1.y + v1.z * v1.z + v1.w * v1.w;
    #pragma unroll
    for (int s = 1; s < 64; s <<= 1) ss += __shfl_xor(ss, s);
    float sc = 1.0f / fmaxf(sqrtf(ss), 1e-12f);
    short8 w;
    w[0] = (short)f2bf(v0.x * sc); w[1] = (short)f2bf(v0.y * sc);
    w[2] = (short)f2bf(v0.z * sc); w[3] = (short)f2bf(v0.w * sc);
    w[4] = (short)f2bf(v1.x * sc); w[5] = (short)f2bf(v1.y * sc);
    w[6] = (short)f2bf(v1.z * sc); w[7] = (short)f2bf(v1.w * sc);
    *reinterpret_cast<short8*>(dst + lane * 8) = w;
  } else if (bid < FB + JB) {
    // e1j: one row (1024 floats) per wave, float4 loads; lane i covers cols
    // [16i,16i+16); word j bit b <-> col 64j+b (standard layout)
    const int row = (bid - FB) * 4 + wid4;
    const float* src = e1j + (size_t)row * P;
    unsigned bits = 0;
    #pragma unroll
    for (int c = 0; c < 4; ++c) {
      float4 v = *(const float4*)(src + lane * 16 + c * 4);
      bits |= ((v.x > 0.5f) ? 1u : 0u) << (c * 4);
      bits |= ((v.y > 0.5f) ? 1u : 0u) << (c * 4 + 1);
      bits |= ((v.z > 0.5f) ? 1u : 0u) << (c * 4 + 2);
      bits |= ((v.w > 0.5f) ? 1u : 0u) << (c * 4 + 3);
    }
    unsigned long long wbits = (unsigned long long)bits << ((lane & 3) * 16);
    wbits |= __shfl_xor(wbits, 1);
    wbits |= __shfl_xor(wbits, 2);
    if ((lane & 3) == 0) bm1j[(size_t)row * 16 + (lane >> 2)] = wbits;
  } else {
    // e1i one-hot position + e2j bitmask: one row per wave
    const int row = (bid - FB - JB) * 4 + wid4;
    unsigned long long b0 = __ballot(e1i[(size_t)row * O + lane] > 0.5f);
    unsigned long long b1 = __ballot(e1i[(size_t)row * O + 64 + lane] > 0.5f);
    unsigned long long d0 = __ballot(e2j[(size_t)row * O + lane] > 0.5f);
    unsigned long long d1 = __ballot(e2j[(size_t)row * O + 64 + lane] > 0.5f);
    if (lane == 0) {
      posr[row] = b0 ? (__ffsll(b0) - 1) : (b1 ? 63 + __ffsll(b1) : -1);
      bm2j[(size_t)row * 2]     = d0;
      bm2j[(size_t)row * 2 + 1] = d1;
    }
  }
}

// ---- main v15: v10 verbatim, launch_bounds(256,4) ------------------------
// Unified reg budget: ~56 VGPR + 64 AGPR acc = ~120 <= 128 cap (4 waves/EU).
// (256,5) cap=102 forced acc spill (r14: WRITE 189MB); (256,3) left occupancy
// at 3 blocks/CU (r10: 35.7%). 128x128 tile, BK=64, 4 waves, acc[2][2].
// grid = 32 batches x 8 rowtiles x 9 coltiles (ct 0 = objects).
__global__ __launch_bounds__(256, 4) void icl_main15(
    const __hip_bfloat16* __restrict__ pn, const __hip_bfloat16* __restrict__ on,
    const unsigned long long* __restrict__ bm1j,
    const unsigned long long* __restrict__ bm2j,
    const int* __restrict__ posr,
    float* __restrict__ d_row, float* __restrict__ s1_row,
    float* __restrict__ s2_row, unsigned long long* __restrict__ pk_row) {

  // XOR-swizzled (pre-swizzled global source): 16B chunk c of row r at c^(r&7)
  __shared__ __hip_bfloat16 As[128 * 64];   // 16 KB
  __shared__ __hip_bfloat16 Bs[128 * 64];   // 16 KB

  const int tid  = threadIdx.x;
  const int l    = tid & 63;
  const int wid  = tid >> 6;
  const int wr   = wid >> 1;    // row-group: rows wr*64..+63
  const int wc   = wid & 1;     // col-group: cols wc*64..+63
  const int half = l >> 5;
  const int l31  = l & 31;

  const int bid   = blockIdx.x;
  const int batch = bid & 31;          // same-batch blocks -> same XCD (b%8)
  const int unit  = bid >> 5;          // 0..71
  const int rt    = unit & 7;          // 8 row tiles
  const int ct    = unit >> 3;         // 9 col tiles (0 = objects)
  const int row0  = rt * 128;

  const __hip_bfloat16* pnb = pn + (size_t)batch * P * D;
  const __hip_bfloat16* onb = on + (size_t)batch * O * D;
  const __hip_bfloat16* asrc = pnb + (size_t)row0 * D;
  const __hip_bfloat16* bsrc = (ct == 0) ? onb : pnb + (size_t)(ct - 1) * 128 * D;

  // stage one 128x64 bf16 tile (1024 16B chunks) via global_load_lds:
  // dest linear (chunk q at byte q*16), source pre-swizzled: gc = c ^ (r&7)
  auto stage = [&](const __hip_bfloat16* __restrict__ src,
                   __hip_bfloat16* __restrict__ lds, int k0) {
    #pragma unroll
    for (int i = 0; i < 4; ++i) {
      int q = i * 256 + tid;
      int rr = q >> 3, c = q & 7;
      int gc = c ^ (rr & 7);
      gld_lds16(src + (size_t)rr * D + k0 + (gc << 3),
                (char*)lds + (size_t)(i * 256 + wid * 64) * 16);
    }
  };

  f32x16 acc[2][2];
  #pragma unroll
  for (int m = 0; m < 2; ++m)
    #pragma unroll
    for (int n = 0; n < 2; ++n)
      #pragma unroll
      for (int k = 0; k < 16; ++k) acc[m][n][k] = 0.f;

  for (int ks = 0; ks < 8; ++ks) {
    __syncthreads();                 // previous step's LDS reads done
    stage(asrc, As, ks * 64);
    stage(bsrc, Bs, ks * 64);
    __syncthreads();                 // staged tiles visible (vmcnt drained)
    #pragma unroll
    for (int kc = 0; kc < 4; ++kc) {
      const int ch = (kc << 1) | half;
      short8 af[2], bfr[2];
      #pragma unroll
      for (int m = 0; m < 2; ++m) {
        int row = wr * 64 + m * 32 + l31;
        af[m] = *reinterpret_cast<const short8*>(
            As + row * 64 + ((ch ^ (row & 7)) << 3));
      }
      #pragma unroll
      for (int n = 0; n < 2; ++n) {
        int col = wc * 64 + n * 32 + l31;
        bfr[n] = *reinterpret_cast<const short8*>(
            Bs + col * 64 + ((ch ^ (col & 7)) << 3));
      }
      #pragma unroll
      for (int m = 0; m < 2; ++m)
        #pragma unroll
        for (int n = 0; n < 2; ++n)
          acc[m][n] = __builtin_amdgcn_mfma_f32_32x32x16_bf16(
              af[m], bfr[n], acc[m][n], 0, 0, 0);
    }
  }

  // ---- epilogue: bitmask row-sums + argmax, atomic combine across blocks --
  if (ct == 0) {
    #pragma unroll
    for (int m = 0; m < 2; ++m) {
      #pragma unroll
      for (int r = 0; r < 16; ++r) {
        const int lrow = wr * 64 + m * 32 + (r & 3) + ((r >> 2) << 3) + (half << 2);
        const size_t grow = (size_t)batch * P + row0 + lrow;
        const int pos = posr[grow];
        const unsigned long long W2 = bm2j[grow * 2 + wc];
        const int c0 = wc * 64 + l31, c1 = c0 + 32;
        float s0 = acc[m][0][r], s1v = acc[m][1][r];
        float e0 = exp2f(s0 * SCL), e1v = exp2f(s1v * SCL);
        float dv  = (c0 == pos ? e0 : 0.f) + (c1 == pos ? e1v : 0.f);
        float s2v = (((W2 >> l31) & 1) ? e0 : 0.f) +
                    (((W2 >> (32 + l31)) & 1) ? e1v : 0.f);
        float mvv; int miv;
        if (s1v > s0) { mvv = s1v; miv = c1; } else { mvv = s0; miv = c0; }
        #pragma unroll
        for (int s = 1; s < 32; s <<= 1) {
          dv  += __shfl_xor(dv, s);
          s2v += __shfl_xor(s2v, s);
          float ov = __shfl_xor(mvv, s);
          int   oi = __shfl_xor(miv, s);
          if (ov > mvv || (ov == mvv && oi < miv)) { mvv = ov; miv = oi; }
        }
        if (l31 == 0) {
          if (dv != 0.f) atomicAdd(&d_row[grow], dv);
          atomicAdd(&s2_row[grow], s2v);
          unsigned long long pkv =
              ((unsigned long long)__float_as_uint(mvv + 2.0f) << 32) |
              (unsigned)(0xFFFFFFFFu - (unsigned)miv);
          atomicMax(&pk_row[grow], pkv);
        }
      }
    }
  } else {
    const int widx = (ct - 1) * 2 + wc;     // u64 word covering this 64-col grp
    #pragma unroll
    for (int m = 0; m < 2; ++m) {
      #pragma unroll
      for (int r = 0; r < 16; ++r) {
        const int lrow = wr * 64 + m * 32 + (r & 3) + ((r >> 2) << 3) + (half << 2);
        const size_t grow = (size_t)batch * P + row0 + lrow;
        const unsigned long long W = bm1j[grow * 16 + widx];
        float v = (((W >> l31) & 1) ? exp2f(acc[m][0][r] * SCL) : 0.f) +
                  (((W >> (32 + l31)) & 1) ? exp2f(acc[m][1][r] * SCL) : 0.f);
        #pragma unroll
        for (int s = 1; s < 32; s <<= 1) v += __shfl_xor(v, s);
        if (l31 == 0 && v != 0.f) atomicAdd(&s1_row[grow], v);
      }
    }
  }
}

// ---------------- per-row loss + scalar reduction --------------------------
__global__ __launch_bounds__(256) void icl_reduce2(
    const float* __restrict__ d_row, const float* __restrict__ s1_row,
    const float* __restrict__ s2_row, const unsigned long long* __restrict__ pk_row,
    const int* __restrict__ posr, float* __restrict__ accum) {
  __shared__ float red[12];
  const int tid = threadIdx.x;
  const int row = blockIdx.x * 256 + tid;
  float d = d_row[row], a = s1_row[row], c = s2_row[row];
  int pos = posr[row];
  int miv = (int)(0xFFFFFFFFu - (unsigned)(pk_row[row] & 0xFFFFFFFFull));
  float valid = (pos >= 0) ? 1.f : 0.f;
  float ratio = d / (d + a + c + EPS);
  float lsum = -logf(ratio + EPS) * valid;
  float lbl  = (pos >= 0 && miv == pos) ? 1.f : 0.f;
  float vct  = valid;
  #pragma unroll
  for (int s = 1; s < 64; s <<= 1) {
    lsum += __shfl_xor(lsum, s);
    lbl  += __shfl_xor(lbl, s);
    vct  += __shfl_xor(vct, s);
  }
  const int wid = tid >> 6;
  if ((tid & 63) == 0) {
    red[wid * 3 + 0] = lsum;
    red[wid * 3 + 1] = lbl;
    red[wid * 3 + 2] = vct;
  }
  __syncthreads();
  if (tid == 0) {
    atomicAdd(&accum[0], red[0] + red[3] + red[6] + red[9]);
    atomicAdd(&accum[1], red[1] + red[4] + red[7] + red[10]);
    atomicAdd(&accum[2], red[2] + red[5] + red[8] + red[11]);
  }
}

__global__ void finalize_kernel(const float* __restrict__ accum,
                                float* __restrict__ out) {
  if (threadIdx.x == 0 && blockIdx.x == 0) {
    float nv = accum[2];
    out[0] = accum[0] / nv;
    out[1] = accum[1] / nv;
  }
}

// ---------------- fallback path (round-1, known correct) -------------------
__global__ __launch_bounds__(256) void norm_kernel(
    const float* __restrict__ pf, const float* __restrict__ of,
    float* __restrict__ invp, float* __restrict__ invo) {
  int lane = threadIdx.x & 63;
  int row = blockIdx.x * 4 + (threadIdx.x >> 6);
  const float* src;
  float* dst;
  if (row < BB * P) {
    src = pf + (size_t)row * D;
    dst = invp + row;
  } else {
    int r = row - BB * P;
    if (r >= BB * O) return;
    src = of + (size_t)r * D;
    dst = invo + r;
  }
  float ss = 0.f;
  #pragma unroll
  for (int i = 0; i < 2; ++i) {
    float4 v = *(const float4*)(src + (lane + 64 * i) * 4);
    ss += v.x * v.x + v.y * v.y + v.z * v.z + v.w * v.w;
  }
  #pragma unroll
  for (int s = 1; s < 64; s <<= 1) ss += __shfl_xor(ss, s);
  if (lane == 0) *dst = 1.0f / fmaxf(sqrtf(ss), 1e-12f);
}

__global__ __launch_bounds__(256) void icl_main_v1(
    const float* __restrict__ pf, const float* __restrict__ of,
    const float* __restrict__ e1i, const float* __restrict__ e1j,
    const float* __restrict__ e2j, const float* __restrict__ invp,
    const float* __restrict__ invo, float* __restrict__ accum) {
  constexpr int PT = 128, BK = 64;
  __shared__ __hip_bfloat16 As[PT * BK];
  __shared__ __hip_bfloat16 Bs[PT * BK];
  __shared__ float d_l[2][PT], s2_l[2][PT], ei_l[2][PT], s1_l[2][PT], mv_l[2][PT];
  __shared__ int   mi_l[2][PT];
  __shared__ float red[12];

  const int tid  = threadIdx.x;
  const int lane = tid & 63;
  const int wid  = tid >> 6;
  const int wr   = wid >> 1;
  const int wc   = wid & 1;
  const int half = lane >> 5;
  const int l31  = lane & 31;
  const int b    = blockIdx.x & 31;
  const int pt   = blockIdx.x >> 5;
  const int row0 = pt * PT;

  const float* pfb = pf + (size_t)b * P * D;
  const float* ofb = of + (size_t)b * O * D;
  const float* ivp = invp + b * P + row0;
  const float* ivq = invp + b * P;
  const float* ivo = invo + b * O;

  float s1p[2][16];
  #pragma unroll
  for (int m = 0; m < 2; ++m)
    #pragma unroll
    for (int r = 0; r < 16; ++r) s1p[m][r] = 0.f;

  auto stage = [&](const float* __restrict__ src, const float* __restrict__ inv,
                   __hip_bfloat16* __restrict__ lds, int k0) {
    #pragma unroll
    for (int i = 0; i < 8; ++i) {
      int c = i * 256 + tid;
      int rr = c >> 4, kc = c & 15;
      float4 v = *(const float4*)(src + (size_t)rr * D + k0 + (kc << 2));
      float s = inv[rr];
      int off = rr * BK + ((((kc >> 1) ^ (rr & 7)) << 3) | ((kc & 1) << 2));
      ushort4 w;
      w.x = f2bf(v.x * s);
      w.y = f2bf(v.y * s);
      w.z = f2bf(v.z * s);
      w.w = f2bf(v.w * s);
      *reinterpret_cast<ushort4*>(lds + off) = w;
    }
  };

  for (int ct = 0; ct < 9; ++ct) {
    const float* bsrc = (ct == 0) ? ofb : pfb + (size_t)(ct - 1) * 128 * D;
    const float* binv = (ct == 0) ? ivo : ivq + (ct - 1) * 128;

    f32x16 acc[2][2];
    #pragma unroll
    for (int m = 0; m < 2; ++m)
      #pragma unroll
      for (int n = 0; n < 2; ++n)
        #pragma unroll
        for (int k = 0; k < 16; ++k) acc[m][n][k] = 0.f;

    for (int ks = 0; ks < D / BK; ++ks) {
      __syncthreads();
      stage(pfb + (size_t)row0 * D, ivp, As, ks * BK);
      stage(bsrc, binv, Bs, ks * BK);
      __syncthreads();
      #pragma unroll
      for (int kc = 0; kc < 4; ++kc) {
        short8 af[2], bfr[2];
        #pragma unroll
        for (int m = 0; m < 2; ++m) {
          int row = wr * 64 + m * 32 + l31;
          af[m] = *reinterpret_cast<const short8*>(
              As + row * BK + ((((kc << 1) | half) ^ (row & 7)) << 3));
        }
        #pragma unroll
        for (int n = 0; n < 2; ++n) {
          int col = wc * 64 + n * 32 + l31;
          bfr[n] = *reinterpret_cast<const short8*>(
              Bs + col * BK + ((((kc << 1) | half) ^ (col & 7)) << 3));
        }
        #pragma unroll
        for (int m = 0; m < 2; ++m)
          #pragma unroll
          for (int n = 0; n < 2; ++n)
            acc[m][n] = __builtin_amdgcn_mfma_f32_32x32x16_bf16(
                af[m], bfr[n], acc[m][n], 0, 0, 0);
      }
    }

    if (ct == 0) {
      #pragma unroll
      for (int m = 0; m < 2; ++m) {
        #pragma unroll
        for (int r = 0; r < 16; ++r) {
          int lrow = wr * 64 + m * 32 + (r & 3) + ((r >> 2) << 3) + (half << 2);
          size_t base = ((size_t)b * P + row0 + lrow) * O;
          float dsum = 0.f, s2s = 0.f, eis = 0.f, mval = -1e30f;
          int midx = 0;
          #pragma unroll
          for (int n = 0; n < 2; ++n) {
            int col = wc * 64 + n * 32 + l31;
            float sim = acc[m][n][r];
            float e = exp2f(sim * SCL);
            float v1 = e1i[base + col];
            float v2 = e2j[base + col];
            dsum += v1 * e;
            s2s  += v2 * e;
            eis  += v1;
            if (sim > mval) { mval = sim; midx = col; }
          }
          #pragma unroll
          for (int s = 1; s < 32; s <<= 1) {
            dsum += __shfl_xor(dsum, s);
            s2s  += __shfl_xor(s2s, s);
            eis  += __shfl_xor(eis, s);
            float ov = __shfl_xor(mval, s);
            int   oi = __shfl_xor(midx, s);
            if (ov > mval || (ov == mval && oi < midx)) { mval = ov; midx = oi; }
          }
          if (l31 == 0) {
            d_l[wc][lrow] = dsum;
            s2_l[wc][lrow] = s2s;
            ei_l[wc][lrow] = eis;
            mv_l[wc][lrow] = mval;
            mi_l[wc][lrow] = midx;
          }
        }
      }
    } else {
      const int qbase = (ct - 1) * 128;
      #pragma unroll
      for (int m = 0; m < 2; ++m) {
        #pragma unroll
        for (int r = 0; r < 16; ++r) {
          int lrow = wr * 64 + m * 32 + (r & 3) + ((r >> 2) << 3) + (half << 2);
          size_t base = ((size_t)b * P + row0 + lrow) * P + qbase;
          float s = 0.f;
          #pragma unroll
          for (int n = 0; n < 2; ++n) {
            int col = wc * 64 + n * 32 + l31;
            s += e1j[base + col] * exp2f(acc[m][n][r] * SCL);
          }
          s1p[m][r] += s;
        }
      }
    }
  }

  #pragma unroll
  for (int m = 0; m < 2; ++m) {
    #pragma unroll
    for (int r = 0; r < 16; ++r) {
      float v = s1p[m][r];
      #pragma unroll
      for (int s = 1; s < 32; s <<= 1) v += __shfl_xor(v, s);
      if (l31 == 0) {
        int lrow = wr * 64 + m * 32 + (r & 3) + ((r >> 2) << 3) + (half << 2);
        s1_l[wc][lrow] = v;
      }
    }
  }
  __syncthreads();

  float lsum = 0.f, lbl = 0.f, vct = 0.f;
  if (tid < PT) {
    float delta = d_l[0][tid] + d_l[1][tid];
    float s2 = s2_l[0][tid] + s2_l[1][tid];
    float eis = ei_l[0][tid] + ei_l[1][tid];
    float s1 = s1_l[0][tid] + s1_l[1][tid];
    float m0 = mv_l[0][tid], m1 = mv_l[1][tid];
    int mi = (m1 > m0) ? mi_l[1][tid] : mi_l[0][tid];
    float valid = (eis > 0.f) ? 1.f : 0.f;
    float ratio = delta / (delta + s1 + s2 + EPS);
    float loss = -logf(ratio + EPS);
    float label = e1i[((size_t)b * P + row0 + tid) * O + mi];
    lsum = loss * valid;
    lbl  = label * valid;
    vct  = valid;
  }
  #pragma unroll
  for (int s = 1; s < 64; s <<= 1) {
    lsum += __shfl_xor(lsum, s);
    lbl  += __shfl_xor(lbl, s);
    vct  += __shfl_xor(vct, s);
  }
  if (lane == 0) {
    red[wid * 3 + 0] = lsum;
    red[wid * 3 + 1] = lbl;
    red[wid * 3 + 2] = vct;
  }
  __syncthreads();
  if (tid == 0) {
    float a = red[0] + red[3] + red[6] + red[9];
    float c = red[1] + red[4] + red[7] + red[10];
    float v = red[2] + red[5] + red[8] + red[11];
    atomicAdd(&accum[0], a);
    atomicAdd(&accum[1], c);
    atomicAdd(&accum[2], v);
  }
}

extern "C" void kernel_launch(void* const* d_in, const int* in_sizes, int n_in,
                              void* d_out, int out_size, void* d_ws, size_t ws_size,
                              hipStream_t stream) {
  const float* pf  = (const float*)d_in[0];
  const float* of  = (const float*)d_in[1];
  const float* e1i = (const float*)d_in[2];
  const float* e1j = (const float*)d_in[3];
  const float* e2j = (const float*)d_in[4];

  char* base = (char*)d_ws;
  constexpr size_t NR = (size_t)BB * P;               // 32768 rows
  float* accum               = (float*)base;                       // 64 B
  float* d_row               = (float*)(base + 64);
  float* s1_row              = (float*)(base + 64 + 4 * NR);
  float* s2_row              = (float*)(base + 64 + 8 * NR);
  unsigned long long* pk_row = (unsigned long long*)(base + 64 + 12 * NR);
  unsigned long long* bm1j   = (unsigned long long*)(base + 64 + 20 * NR); // 128B/row
  unsigned long long* bm2j   = (unsigned long long*)(base + 64 + 148 * NR); // 16B/row
  int* posr                  = (int*)(base + 64 + 164 * NR);
  __hip_bfloat16* pn         = (__hip_bfloat16*)(base + 64 + 168 * NR);
  const size_t pn_bytes = (size_t)BB * P * D * 2;
  const size_t on_bytes = (size_t)BB * O * D * 2;
  __hip_bfloat16* on         = (__hip_bfloat16*)(base + 64 + 168 * NR + pn_bytes);
  const size_t need = 64 + 168 * NR + pn_bytes + on_bytes;

  if (ws_size >= need) {
    hipMemsetAsync(base, 0, 64 + 20 * NR, stream);      // accum,d,s1,s2,pk
    prep2_kernel<<<FB + 2 * JB, 256, 0, stream>>>(pf, of, e1i, e1j, e2j,
                                                  pn, on, bm1j, bm2j, posr);
    icl_main15<<<BB * 72, 256, 0, stream>>>(pn, on, bm1j, bm2j, posr,
                                            d_row, s1_row, s2_row, pk_row);
    icl_reduce2<<<NR / 256, 256, 0, stream>>>(d_row, s1_row, s2_row, pk_row,
                                              posr, accum);
  } else {
    float* ws   = (float*)d_ws;
    float* invp = ws + 16;
    float* invo = ws + 16 + BB * P;
    hipMemsetAsync(accum, 0, 16 * sizeof(float), stream);
    norm_kernel<<<(BB * P + BB * O) / 4, 256, 0, stream>>>(pf, of, invp, invo);
    icl_main_v1<<<BB * (P / 128), 256, 0, stream>>>(pf, of, e1i, e1j, e2j,
                                                    invp, invo, accum);
  }
  finalize_kernel<<<1, 64, 0, stream>>>(accum, (float*)d_out);
}